// Round 12
// baseline (59.513 us; speedup 1.0000x reference)
//
#include <hip/hip_runtime.h>
#include <math.h>

// Problem shape (fixed by the reference setup_inputs):
#define B_DIM  8
#define T_DIM  256
#define U_DIM  100
#define U1_DIM 101
#define V_DIM  128

// comb: diagonal-major packed single-step operands (log2 domain, bf16):
//   cell (d,u) uint32: lo = bl(d-1-u, u) [BL_d[u]], hi = em(d-u, u-1) [EM_d[u]].
// Row = ROWU uints = 512 B. NO pre-fill: invalid/unwritten cells hold garbage
// (finite bf16) and every consumer masks by (t,u) validity arithmetically.
#define ROWU   128
#define DROWS  360
#define NEGF   (-8.0e29f)
#define LOG2E  1.4426950408889634f
#define LN2    0.69314718055994530942f

// dp LDS: 4-step banded weight rows, built in-kernel. Row = 312 uints (1248 B):
// plane0 = V0|V1 (104 uints), plane1 = V2|V3, plane2 = V4.
#define VROWU  312
#define NITMAX 88
#define LDS_BYTES (NITMAX * VROWU * 4)   // 109,824

typedef unsigned uv2 __attribute__((ext_vector_type(2)));

__device__ __forceinline__ float ubit(unsigned u) { return __builtin_bit_cast(float, u); }

__device__ __forceinline__ float logadd2(float a, float b) {
    float m = fmaxf(a, b);
    float e = exp2f(-fabsf(a - b));
    return m + log2f(1.0f + e);
}
__device__ __forceinline__ float lse3(float a, float b, float c) {
    float m = fmaxf(fmaxf(a, b), c);
    float s = exp2f(a - m) + exp2f(b - m) + exp2f(c - m);
    return m + log2f(s);
}
__device__ __forceinline__ float lse5(float a, float b, float c, float d, float e) {
    float m = fmaxf(fmaxf(fmaxf(a, b), c), fmaxf(d, e));
    float s = exp2f(a - m) + exp2f(b - m) + exp2f(c - m) + exp2f(d - m) + exp2f(e - m);
    return m + log2f(s);
}

// lane l <- lane l-1 (lane 0 gets 0), pure-VALU DPP wave_shr:1
__device__ __forceinline__ float lane_shr1(float x) {
    int r = __builtin_amdgcn_update_dpp(0, __builtin_bit_cast(int, x),
                                        0x138 /*wave_shr:1*/, 0xF, 0xF, true);
    return __builtin_bit_cast(float, r);
}

// fp32 -> bf16 (round-to-nearest-even)
__device__ __forceinline__ unsigned f2bf(float f) {
    unsigned u = __builtin_bit_cast(unsigned, f);
    u += 0x7FFF + ((u >> 16) & 1);
    return u >> 16;
}

// Kernel 1: log-softmax over V=128 per (b,t,u) row, LOG2 domain, bf16 out.
// One 32-lane half-wave per row, float4 per lane. Rows with t>tl or u>ul are
// skipped entirely (consumers mask by validity, so no fill needed).
__global__ __launch_bounds__(256) void lsm_kernel(
    const float* __restrict__ acts, const int* __restrict__ labels,
    const int* __restrict__ act_lens, const int* __restrict__ label_lens,
    unsigned short* __restrict__ comb, int* __restrict__ counter, int nrows)
{
    if (blockIdx.x == 0 && threadIdx.x == 0) *counter = 0;   // finalize sem reset

    int rid = blockIdx.x * 8 + (threadIdx.x >> 5);   // 8 rows per 256-thr block
    if (rid >= nrows) return;
    int hl = threadIdx.x & 31;                        // lane within 32-half

    int u  = rid % U1_DIM;
    int bt = rid / U1_DIM;          // b*T + t
    int b  = bt / T_DIM;
    int t  = bt - b * T_DIM;
    if (t >= act_lens[b] || u > label_lens[b]) return;   // uniform per half-wave

    const float* row = acts + (size_t)rid * V_DIM;
    float4 x = *reinterpret_cast<const float4*>(row + 4 * hl);
    float4 y = make_float4(x.x * LOG2E, x.y * LOG2E, x.z * LOG2E, x.w * LOG2E);

    float s = exp2f(y.x) + exp2f(y.y) + exp2f(y.z) + exp2f(y.w);
    #pragma unroll
    for (int off = 16; off; off >>= 1) s += __shfl_xor(s, off);
    float lse2 = log2f(s);

    unsigned short* C = comb + (size_t)b * DROWS * (ROWU * 2);
    int d = t + u + 1;              // both outputs land on this diagonal row

    if (hl == 0)                    // bl(t,u) -> cell u low half
        C[(size_t)d * (ROWU * 2) + 2 * u] = (unsigned short)f2bf(y.x - lse2);
    if (u < U_DIM) {
        int lab = labels[b * U_DIM + u];              // 0..127
        if (hl == (lab >> 2)) {
            int r = lab & 3;
            float v = (r == 0) ? y.x : (r == 1) ? y.y : (r == 2) ? y.z : y.w;
            // em(t,u) -> cell u+1 high half
            C[(size_t)d * (ROWU * 2) + 2 * u + 3] = (unsigned short)f2bf(v - lse2);
        }
    }
}

// 2-step weights alpha_{d-2} -> alpha_d with arithmetic validity masking.
// BL_d[u] valid iff 0 <= d-1-u <= tl && u <= ul; EM_d[u] iff 0 <= d-u <= tl
// && 1 <= u <= ul. Invalid/garbage operands forced to NEGF (finite math).
struct W2 { float tA, mA, lA, tB, mB, lB; };
__device__ __forceinline__ W2 buildW2m(uv2 c0, uv2 cm, int l, int d, int tl, int ul) {
    const int ua = 2 * l, ub = 2 * l + 1;
    float BL0a = ubit(c0.x << 16), EM0a = ubit(c0.x & 0xFFFF0000u);
    float BL0b = ubit(c0.y << 16), EM0b = ubit(c0.y & 0xFFFF0000u);
    float BLma = ubit(cm.x << 16), EMma = ubit(cm.x & 0xFFFF0000u);
    float BLmb = ubit(cm.y << 16), EMmb = ubit(cm.y & 0xFFFF0000u);
    BL0a = (ua <= ul && (unsigned)(d - 1 - ua) <= (unsigned)tl) ? BL0a : NEGF;
    BL0b = (ub <= ul && (unsigned)(d - 1 - ub) <= (unsigned)tl) ? BL0b : NEGF;
    EM0a = (ua >= 1 && ua <= ul && (unsigned)(d - ua) <= (unsigned)tl) ? EM0a : NEGF;
    EM0b = (ub <= ul && (unsigned)(d - ub) <= (unsigned)tl) ? EM0b : NEGF;  // ub>=1 always
    BLma = (ua <= ul && (unsigned)(d - 2 - ua) <= (unsigned)tl) ? BLma : NEGF;
    BLmb = (ub <= ul && (unsigned)(d - 1 - ub) <= (unsigned)tl) ? BLmb : NEGF;
    EMma = (ua >= 1 && ua <= ul && (unsigned)(d - 1 - ua) <= (unsigned)tl) ? EMma : NEGF;
    EMmb = (ub <= ul && (unsigned)(d - 1 - ub) <= (unsigned)tl) ? EMmb : NEGF;
    float BLmp = lane_shr1(BLmb), EMmp = lane_shr1(EMmb);   // cell 2l-1 of row d-1
    W2 w;
    w.tA = BLma + BL0a;
    w.mA = logadd2(EMma + BL0a, BLmp + EM0a);
    w.lA = EMmp + EM0a;
    w.tB = BLmb + BL0b;
    w.mB = logadd2(EMmb + BL0b, BLma + EM0b);
    w.lB = EMma + EM0b;
    if (l == 0) { w.mA = NEGF; w.lA = NEGF; w.lB = NEGF; }  // u=0/1 boundaries
    return w;
}

// Kernel 2: FUSED v+dp, one 512-thread block per batch.
// Phase 1 (8 waves): build the ~88 needed 4-step weight rows (V[dt],
// dt = start+4(it+1)) from comb into LDS — the R11 v_kernel algebra verbatim,
// but only the rows this batch's parity class consumes (R11 built 4x more).
// Phase 2 (wave 0 only, after one barrier): 44..88 serial LSE5 steps entirely
// from LDS (zero vmem in the loop), neighbors via 4 chained DPP shifts.
// Final reduction fused via device-scope counter (reset for next replay).
__global__ __launch_bounds__(512, 1) void dp_kernel(
    const unsigned* __restrict__ comb,
    const int* __restrict__ act_lens, const int* __restrict__ label_lens,
    float* __restrict__ loglike, int* __restrict__ counter,
    float* __restrict__ out)
{
    extern __shared__ unsigned sV[];            // NITMAX rows x 312 uints

    const int b = blockIdx.x;
    const int l = threadIdx.x & 63;
    const int w = threadIdx.x >> 6;             // wave 0..7
    const int tl    = act_lens[b] - 1;
    const int ul    = label_lens[b];
    const int dfin  = tl + ul;                  // in [177, 355]
    const int start = dfin & 3;
    const int niter = dfin >> 2;                // 44..88 composed steps

    const unsigned* combB = comb + (size_t)b * DROWS * ROWU;

    // ---- Phase 1: build V rows it = 0..niter-1 (wave-parallel) ----
    for (int it = w; it < niter; it += 8) {
        const int dt = start + 4 * (it + 1);    // target diagonal (<= dfin)
        const unsigned* C = combB + (size_t)dt * ROWU + 2 * l;
        uv2 c0 = *(const uv2*)(C);
        uv2 c1 = *(const uv2*)(C - ROWU);
        uv2 c2 = *(const uv2*)(C - 2 * ROWU);
        uv2 c3 = *(const uv2*)(C - 3 * ROWU);

        W2 P = buildW2m(c0, c1, l, dt,     tl, ul);   // alpha_{dt-2} -> alpha_dt
        W2 Q = buildW2m(c2, c3, l, dt - 2, tl, ul);   // alpha_{dt-4} -> alpha_{dt-2}

        float Qt_b1 = lane_shr1(Q.tB), Qm_b1 = lane_shr1(Q.mB), Ql_b1 = lane_shr1(Q.lB);
        float Qt_a1 = lane_shr1(Q.tA), Qm_a1 = lane_shr1(Q.mA), Ql_a1 = lane_shr1(Q.lA);

        float V0a = P.tA + Q.tA;
        float V1a = logadd2(P.tA + Q.mA, P.mA + Qt_b1);
        float V2a = lse3(P.tA + Q.lA, P.mA + Qm_b1, P.lA + Qt_a1);
        float V3a = logadd2(P.mA + Ql_b1, P.lA + Qm_a1);
        float V4a = P.lA + Ql_a1;
        float V0b = P.tB + Q.tB;
        float V1b = logadd2(P.tB + Q.mB, P.mB + Q.tA);
        float V2b = lse3(P.tB + Q.lB, P.mB + Q.mA, P.lB + Qt_b1);
        float V3b = logadd2(P.mB + Q.lA, P.lB + Qm_b1);
        float V4b = P.lB + Ql_b1;
        if (l == 0) { V1a = NEGF; V2a = NEGF; V3a = NEGF; V4a = NEGF; }

        if (l < 52) {
            unsigned* ro = sV + it * VROWU;
            ro[2 * l]           = f2bf(V0a) | (f2bf(V1a) << 16);
            ro[2 * l + 1]       = f2bf(V0b) | (f2bf(V1b) << 16);
            ro[104 + 2 * l]     = f2bf(V2a) | (f2bf(V3a) << 16);
            ro[104 + 2 * l + 1] = f2bf(V2b) | (f2bf(V3b) << 16);
            ro[208 + 2 * l]     = f2bf(V4a);
            ro[208 + 2 * l + 1] = f2bf(V4b);
        }
    }
    __syncthreads();
    if (w != 0) return;

    // ---- Phase 2: serial chain (wave 0), LDS-only operands ----
    // final blank term bl(tl,ul): comb row dfin+1, cell ul, low half (valid by defn)
    float fin_bl = ubit(combB[(size_t)(dfin + 1) * ROWU + ul] << 16);

    float v0 = (l == 0) ? 0.0f : NEGF;          // diag 0: alpha[0,0]=0
    float v1 = NEGF;
    // masked manual single steps to reach diag `start` (<= 3 iters)
    for (int d = 1; d <= start; ++d) {
        uv2 c = *(const uv2*)(combB + (size_t)d * ROWU + 2 * l);
        const int ua = 2 * l, ub = 2 * l + 1;
        float bl0 = ubit(c.x << 16), em0 = ubit(c.x & 0xFFFF0000u);
        float bl1 = ubit(c.y << 16), em1 = ubit(c.y & 0xFFFF0000u);
        bl0 = (ua <= ul && (unsigned)(d - 1 - ua) <= (unsigned)tl) ? bl0 : NEGF;
        bl1 = (ub <= ul && (unsigned)(d - 1 - ub) <= (unsigned)tl) ? bl1 : NEGF;
        em0 = (ua >= 1 && ua <= ul && (unsigned)(d - ua) <= (unsigned)tl) ? em0 : NEGF;
        em1 = (ub <= ul && (unsigned)(d - ub) <= (unsigned)tl) ? em1 : NEGF;
        float left0 = lane_shr1(v1);
        float a0 = v0 + bl0, p0 = left0 + em0;
        float a1 = v1 + bl1, p1 = v0 + em1;
        v0 = logadd2(a0, p0);
        v1 = logadd2(a1, p1);
    }

    #pragma unroll 4
    for (int it = 0; it < niter; ++it) {
        const unsigned* ro = sV + it * VROWU;
        uv2 a0 = *(const uv2*)(ro + 2 * l);
        uv2 a1 = *(const uv2*)(ro + 104 + 2 * l);
        uv2 a2 = *(const uv2*)(ro + 208 + 2 * l);
        float V0a = ubit(a0.x << 16), V1a = ubit(a0.x & 0xFFFF0000u);
        float V0b = ubit(a0.y << 16), V1b = ubit(a0.y & 0xFFFF0000u);
        float V2a = ubit(a1.x << 16), V3a = ubit(a1.x & 0xFFFF0000u);
        float V2b = ubit(a1.y << 16), V3b = ubit(a1.y & 0xFFFF0000u);
        float V4a = ubit(a2.x << 16), V4b = ubit(a2.y << 16);
        float s1 = lane_shr1(v1);   // alpha[2l-1]
        float s0 = lane_shr1(v0);   // alpha[2l-2]
        float s3 = lane_shr1(s1);   // alpha[2l-3]
        float s2 = lane_shr1(s0);   // alpha[2l-4]
        float nA = lse5(v0 + V0a, s1 + V1a, s0 + V2a, s3 + V3a, s2 + V4a);
        float nB = lse5(v1 + V0b, v0 + V1b, s1 + V2b, s0 + V3b, s3 + V4b);
        v0 = nA; v1 = nB;
    }
    // loop ends exactly at diag dfin: v0/v1 hold alpha[dfin]

    float res = (ul & 1) ? v1 : v0;             // alpha[tl,ul] in lane ul>>1
    if (l == (ul >> 1)) {
        loglike[b] = LN2 * (res + fin_bl);
        __threadfence();                         // publish before signaling
        int old = atomicAdd(counter, 1);         // device-scope
        if (old == B_DIM - 1) {                  // last block finalizes
            __threadfence();
            float s = 0.0f;
            #pragma unroll
            for (int i = 0; i < B_DIM; ++i)
                s += __hip_atomic_load(&loglike[i], __ATOMIC_RELAXED,
                                       __HIP_MEMORY_SCOPE_AGENT);
            out[0] = -s / (float)B_DIM;
            __hip_atomic_store(counter, 0, __ATOMIC_RELAXED,
                               __HIP_MEMORY_SCOPE_AGENT);   // clean for next replay
        }
    }
}

extern "C" void kernel_launch(void* const* d_in, const int* in_sizes, int n_in,
                              void* d_out, int out_size, void* d_ws, size_t ws_size,
                              hipStream_t stream) {
    const float* acts       = (const float*)d_in[0];
    const int*   labels     = (const int*)d_in[1];
    const int*   act_lens   = (const int*)d_in[2];
    const int*   label_lens = (const int*)d_in[3];

    unsigned* comb    = (unsigned*)d_ws;                      // 1.47 MB
    float*    loglike = (float*)(comb + (size_t)B_DIM * DROWS * ROWU);
    int*      counter = (int*)(loglike + B_DIM);

    int nrows   = B_DIM * T_DIM * U1_DIM;                     // 206,848
    int nblocks = (nrows + 7) / 8;                            // 8 rows per block

    // allow >64KB dynamic LDS (110 KB; CU has 160 KB) — host-side, capture-safe
    hipFuncSetAttribute(reinterpret_cast<const void*>(dp_kernel),
                        hipFuncAttributeMaxDynamicSharedMemorySize, LDS_BYTES);

    lsm_kernel<<<nblocks, 256, 0, stream>>>(acts, labels, act_lens, label_lens,
                                            (unsigned short*)comb, counter, nrows);
    dp_kernel<<<B_DIM, 512, LDS_BYTES, stream>>>(comb, act_lens, label_lens,
                                                 loglike, counter, (float*)d_out);
}